// Round 10
// baseline (197.294 us; speedup 1.0000x reference)
//
#include <hip/hip_runtime.h>

#define NN 100000   // nodes
#define NE 1000000  // edges
#define FD 64       // feature dim
#define CHK 64      // nodes per block tile
#define NCH 50000   // nodes per chunk (2 chunks; sumbuf sized for one chunk)
#define NBLK 98     // scan blocks: ceil(NN/1024)

// ws layout (4-byte units):
//   deg      : [0, NN)              int
//   rowstart : [NN, 2NN)            int   (exclusive scan of deg)
//   partial  : [2NN, 2NN+128)       int   (scan block sums)
//   rank     : [2NN+128, +NE)       int   (edge rank within its dst row)
//   csr      : [2NN+128+NE, +NE)    int   (src ids grouped by dst)
//   pq       : [2NN+128+2NE, +4NN)  float (p0,p1,q0,q1 per node)
//   wt       : next, 2*4096 floats  (W1l^T, W1r^T: [j][k] layouts)
//   sumbuf   : next, NCH*64 floats  (layer-1 neighbor means, per chunk)
// total ~ 23.3 MB (<= 28.4 MB proven in R1)

#define OFF_DEG 0
#define OFF_ROW (NN)
#define OFF_PAR (2 * NN)
#define OFF_RANK (2 * NN + 128)
#define OFF_CSR (2 * NN + 128 + NE)
#define OFF_PQ  (2 * NN + 128 + 2 * NE)
#define OFF_WT  (2 * NN + 128 + 2 * NE + 4 * NN)
#define OFF_SUM (OFF_WT + 2 * FD * FD)

// ---------------------------------------------------------------------------
// K1 (fused): edge_index -> float output tail, in-degree atomics + rank,
// and layer-1 weight transpose. ONE pass over ei (deg pre-zeroed by memset).
__global__ void k_ip(const int* __restrict__ ei, float* __restrict__ edge_out,
                     int* __restrict__ deg, int* __restrict__ rank,
                     const float* __restrict__ W1l, const float* __restrict__ W1r,
                     float* __restrict__ wt1l, float* __restrict__ wt1r) {
    const int tid = blockIdx.x * blockDim.x + threadIdx.x;
    if (tid < 2 * NE / 4) {
        const int4 v = *((const int4*)ei + tid);
        float4 f;
        f.x = (float)v.x; f.y = (float)v.y; f.z = (float)v.z; f.w = (float)v.w;
        *((float4*)edge_out + tid) = f;
        if (tid >= NE / 4) {  // dst half: degree count + rank
            int4 r;
            r.x = atomicAdd(&deg[v.x], 1);
            r.y = atomicAdd(&deg[v.y], 1);
            r.z = atomicAdd(&deg[v.z], 1);
            r.w = atomicAdd(&deg[v.w], 1);
            *((int4*)rank + (tid - NE / 4)) = r;
        }
    }
    if (tid < FD * FD) {
        const int k = tid >> 6, j = tid & 63;
        wt1l[j * FD + k] = W1l[tid];
        wt1r[j * FD + k] = W1r[tid];
    }
}

// ---------------------------------------------------------------------------
// K2a: per-block (1024-elem) sums of deg -> partial[b]
__global__ __launch_bounds__(256) void k_scanA(const int* __restrict__ deg,
                                               int* __restrict__ partial) {
    __shared__ int lds[256];
    int t = threadIdx.x;
    int base = blockIdx.x * 1024 + t * 4;
    int s_t = 0;
    if (base < NN) {  // NN % 4 == 0
        int4 v = *(const int4*)(deg + base);
        s_t = v.x + v.y + v.z + v.w;
    }
    lds[t] = s_t;
    __syncthreads();
    for (int s = 128; s; s >>= 1) {
        if (t < s) lds[t] += lds[t + s];
        __syncthreads();
    }
    if (t == 0) partial[blockIdx.x] = lds[0];
}

// K2b: block offset + intra-block exclusive scan -> rowstart[i]
__global__ __launch_bounds__(256) void k_scanB(const int* __restrict__ deg,
                                               const int* __restrict__ partial,
                                               int* __restrict__ rowstart) {
    __shared__ int lds[256];
    int t = threadIdx.x, b = blockIdx.x;
    lds[t] = (t < b && t < NBLK) ? partial[t] : 0;
    __syncthreads();
    for (int s = 128; s; s >>= 1) {
        if (t < s) lds[t] += lds[t + s];
        __syncthreads();
    }
    int bo = lds[0];
    __syncthreads();

    int base = b * 1024 + t * 4;
    int4 v = make_int4(0, 0, 0, 0);
    if (base < NN) v = *(const int4*)(deg + base);
    int s_t = v.x + v.y + v.z + v.w;

    lds[t] = s_t;
    __syncthreads();
    for (int off = 1; off < 256; off <<= 1) {
        int v2 = lds[t];
        if (t >= off) v2 += lds[t - off];
        __syncthreads();
        lds[t] = v2;
        __syncthreads();
    }
    int excl = lds[t] - s_t;
    if (base < NN) {
        int r = bo + excl;
        int4 out;
        out.x = r;
        out.y = r + v.x;
        out.z = r + v.x + v.y;
        out.w = r + v.x + v.y + v.z;
        *(int4*)(rowstart + base) = out;
    }
}

// ---------------------------------------------------------------------------
// K3: pure scatter (no atomics), int4 streaming reads, 4 edges/thread.
__global__ void k_build(const int* __restrict__ ei, const int* __restrict__ rowstart,
                        const int* __restrict__ rank, int* __restrict__ csr) {
    const int i = blockIdx.x * blockDim.x + threadIdx.x;
    if (i >= NE / 4) return;
    const int4 s = *((const int4*)ei + i);
    const int4 d = *((const int4*)(ei + NE) + i);
    const int4 r = *((const int4*)rank + i);
    csr[rowstart[d.x] + r.x] = s.x;
    csr[rowstart[d.y] + r.y] = s.y;
    csr[rowstart[d.z] + r.z] = s.z;
    csr[rowstart[d.w] + r.w] = s.w;
}

// ---------------------------------------------------------------------------
// K4: neighbor-mean gather ONLY (no LDS, no barrier -> occupancy bound only
//  by waves). Wave = 4 groups of 16 lanes; group owns one node per round and
//  fetches whole 256B neighbor rows as float4 via 32-bit byte offsets
//  (shfl the OFFSET -> saddr-form loads, ~3 fewer VALU/edge). 8-deep
//  register batches fenced by sched_barrier(0).
__global__ __launch_bounds__(512, 4) void k_aggr(
    const int* __restrict__ csr, const int* __restrict__ rowstart,
    const int* __restrict__ deg, const float* __restrict__ x,
    float* __restrict__ sumbuf, int n0, int n1) {
    const int lane = threadIdx.x & 63;
    const int wid = threadIdx.x >> 6;   // 0..7
    const int g = lane >> 4;            // group 0..3
    const int sl = lane & 15;           // lane within group
    const int gb = g << 4;              // group base lane
    const int base = n0 + blockIdx.x * CHK;
    const char* xb = (const char*)x;
    const unsigned slb = (unsigned)(sl << 4);

    for (int r = 0; r < 2; ++r) {
        const int nl = wid * 8 + r * 4 + g;  // 0..63
        const int n = base + nl;
        const bool ok = n < n1;
        const int nn = ok ? n : n1 - 1;
        const int d = deg[nn];               // group-uniform
        const int rs = rowstart[nn];
        float4 acc = make_float4(0.f, 0.f, 0.f, 0.f);

        int dmax = d;
        dmax = max(dmax, __shfl_xor(dmax, 16));
        dmax = max(dmax, __shfl_xor(dmax, 32));
        const int dmaxu = __builtin_amdgcn_readfirstlane(dmax);  // wave max
        const int nch = (dmaxu + 15) >> 4;

        for (int c = 0; c < nch; ++c) {
            const int jb = c << 4;
            const int ia = min(rs + jb + sl, NE - 1);
            const unsigned off = ((unsigned)csr[ia]) << 8;  // byte offset of row
            const int rem = d - jb;           // group-uniform (may be <=0)
            const int rc = max(rem - 1, 0);   // clamp index
#pragma unroll
            for (int half = 0; half < 2; ++half) {
                if (half == 1 && (dmaxu - jb) <= 8) break;  // wave-uniform skip
                float4 buf[8];
#pragma unroll
                for (int t = 0; t < 8; ++t) {
                    const int jt = half * 8 + t;
                    const int sj = min(jt, rc);
                    const unsigned ob = (unsigned)__shfl((int)off, gb + sj);
                    buf[t] = *(const float4*)(xb + (size_t)(ob + slb));
                }
                __builtin_amdgcn_sched_barrier(0);  // keep 8 loads in flight
#pragma unroll
                for (int t = 0; t < 8; ++t) {
                    const int jt = half * 8 + t;
                    const float m = (jt < rem) ? 1.f : 0.f;
                    acc.x += m * buf[t].x;
                    acc.y += m * buf[t].y;
                    acc.z += m * buf[t].z;
                    acc.w += m * buf[t].w;
                }
            }
        }
        if (ok) {
            const float inv = 1.0f / (float)max(d, 1);
            acc.x *= inv; acc.y *= inv; acc.z *= inv; acc.w *= inv;
            *(float4*)(sumbuf + (size_t)(n - n0) * FD + sl * 4) = acc;
        }
    }
}

// ---------------------------------------------------------------------------
// K5: dense MLP over a node chunk. 64-node tile per block (8 waves).
//  load: coalesced float4 reads of sumbuf (means) + x rows -> transposed LDS.
//  phase B: lane = node, wave w covers k-slice [8w, 8w+8); wave-uniform
//  (scalar) weight loads; relu + W2 fold per-lane; LDS-atomic combine.
__global__ __launch_bounds__(512, 4) void k_mlp(
    const float* __restrict__ x, const float* __restrict__ sumbuf,
    const float* __restrict__ wt1l, const float* __restrict__ b1,
    const float* __restrict__ wt1r,
    const float* __restrict__ W2l, const float* __restrict__ b2,
    const float* __restrict__ W2r,
    float* __restrict__ pq, int n0, int n1) {
    __shared__ float sT[FD][CHK + 1];   // aggr, transposed
    __shared__ float xT[FD][CHK + 1];   // self x, transposed
    __shared__ float pacc[4 * CHK];
    const int lane = threadIdx.x & 63;
    const int wid = threadIdx.x >> 6;   // 0..7
    const int g = lane >> 4;
    const int sl = lane & 15;
    const int base = n0 + blockIdx.x * CHK;

    if (threadIdx.x < 4 * CHK) pacc[threadIdx.x] = 0.f;

    for (int r = 0; r < 2; ++r) {
        const int nl = wid * 8 + r * 4 + g;
        const int n = base + nl;
        if (n < n1) {
            const float4 sv = *(const float4*)(sumbuf + (size_t)(n - n0) * FD + sl * 4);
            const float4 xv = *(const float4*)(x + (size_t)n * FD + sl * 4);
            const int f = sl * 4;
            sT[f + 0][nl] = sv.x;
            sT[f + 1][nl] = sv.y;
            sT[f + 2][nl] = sv.z;
            sT[f + 3][nl] = sv.w;
            xT[f + 0][nl] = xv.x;
            xT[f + 1][nl] = xv.y;
            xT[f + 2][nl] = xv.z;
            xT[f + 3][nl] = xv.w;
        }
    }
    __syncthreads();

    // ---- phase B: lane = node, k-slice [kbase, kbase+8) ----
    const int kbase = __builtin_amdgcn_readfirstlane(wid * 8);
    float h[8];
#pragma unroll
    for (int t = 0; t < 8; ++t) h[t] = b1[kbase + t];
#pragma unroll 4
    for (int j = 0; j < FD; ++j) {
        const float sj = sT[j][lane];
        const float xj = xT[j][lane];
        const float* wl = wt1l + j * FD + kbase;
        const float* wr = wt1r + j * FD + kbase;
#pragma unroll
        for (int t = 0; t < 8; ++t) h[t] += sj * wl[t] + xj * wr[t];
    }

    float p0 = 0.f, p1 = 0.f, q0 = 0.f, q1 = 0.f;
#pragma unroll
    for (int t = 0; t < 8; ++t) {
        const float r = fmaxf(h[t], 0.f);
        p0 += r * W2l[kbase + t];
        p1 += r * W2l[FD + kbase + t];
        q0 += r * W2r[kbase + t];
        q1 += r * W2r[FD + kbase + t];
    }
    atomicAdd(&pacc[0 * CHK + lane], p0);
    atomicAdd(&pacc[1 * CHK + lane], p1);
    atomicAdd(&pacc[2 * CHK + lane], q0);
    atomicAdd(&pacc[3 * CHK + lane], q1);
    __syncthreads();

    // ---- write pq: thread t -> (node t>>2, comp t&3), coalesced ----
    {
        const int t = threadIdx.x;
        if (t < 4 * CHK) {
            const int n = base + (t >> 2);
            if (n < n1) {
                const int c = t & 3;
                float v = pacc[c * CHK + (t >> 2)];
                if (c == 2) v += b2[0];
                if (c == 3) v += b2[1];
                pq[(size_t)n * 4 + c] = v;
            }
        }
    }
}

// ---------------------------------------------------------------------------
// K6: layer-2 mean aggregation of p + final add. 16 lanes per node,
//     4 nodes per wave.
__global__ void k_l2(const int* __restrict__ csr, const int* __restrict__ rowstart,
                     const int* __restrict__ deg, const float* __restrict__ pq,
                     float* __restrict__ out) {
    const int gw = (blockIdx.x * blockDim.x + threadIdx.x) >> 6;
    const int lane = threadIdx.x & 63;
    const int sub = lane >> 4;   // node within wave
    const int sl = lane & 15;    // lane within 16-group
    const int n = gw * 4 + sub;
    if (n >= NN) return;
    const int rs = rowstart[n];
    const int d = deg[n];
    float a0 = 0.f, a1 = 0.f;
    for (int i = sl; i < d; i += 16) {
        const int s = csr[rs + i];
        const float2 v = *(const float2*)(pq + 4 * (size_t)s);
        a0 += v.x;
        a1 += v.y;
    }
#pragma unroll
    for (int off = 8; off; off >>= 1) {
        a0 += __shfl_xor(a0, off);
        a1 += __shfl_xor(a1, off);
    }
    if (sl == 0) {
        const float inv = 1.0f / (float)max(d, 1);
        const float2 q = *(const float2*)(pq + 4 * (size_t)n + 2);
        *(float2*)(out + 2 * (size_t)n) = make_float2(a0 * inv + q.x, a1 * inv + q.y);
    }
}

// ---------------------------------------------------------------------------
extern "C" void kernel_launch(void* const* d_in, const int* in_sizes, int n_in,
                              void* d_out, int out_size, void* d_ws, size_t ws_size,
                              hipStream_t stream) {
    const float* x   = (const float*)d_in[0];
    const int*   ei  = (const int*)d_in[1];
    const float* W1l = (const float*)d_in[2];
    const float* b1  = (const float*)d_in[3];
    const float* W1r = (const float*)d_in[4];
    const float* W2l = (const float*)d_in[5];
    const float* b2  = (const float*)d_in[6];
    const float* W2r = (const float*)d_in[7];

    float* out      = (float*)d_out;   // N*2 floats
    float* edge_out = out + 2 * NN;    // 2*E floats (edge_index as float)

    int*   wsi      = (int*)d_ws;
    int*   deg      = wsi + OFF_DEG;
    int*   rowstart = wsi + OFF_ROW;
    int*   partial  = wsi + OFF_PAR;
    int*   rank     = wsi + OFF_RANK;
    int*   csr      = wsi + OFF_CSR;
    float* pq       = (float*)d_ws + OFF_PQ;
    float* wt1l     = (float*)d_ws + OFF_WT;
    float* wt1r     = wt1l + FD * FD;
    float* sumbuf   = (float*)d_ws + OFF_SUM;

    hipMemsetAsync(deg, 0, (size_t)NN * sizeof(int), stream);
    k_ip<<<(2 * NE / 4 + 255) / 256, 256, 0, stream>>>(
        ei, edge_out, deg, rank, W1l, W1r, wt1l, wt1r);
    k_scanA<<<NBLK, 256, 0, stream>>>(deg, partial);
    k_scanB<<<NBLK, 256, 0, stream>>>(deg, partial, rowstart);
    k_build<<<(NE / 4 + 255) / 256, 256, 0, stream>>>(ei, rowstart, rank, csr);

    for (int c = 0; c < 2; ++c) {
        const int n0 = c * NCH;
        const int n1 = min(n0 + NCH, NN);
        const int nb = (n1 - n0 + CHK - 1) / CHK;
        k_aggr<<<nb, 512, 0, stream>>>(csr, rowstart, deg, x, sumbuf, n0, n1);
        k_mlp<<<nb, 512, 0, stream>>>(x, sumbuf, wt1l, b1, wt1r,
                                      W2l, b2, W2r, pq, n0, n1);
    }

    k_l2<<<((NN + 3) / 4 * 64 + 255) / 256, 256, 0, stream>>>(
        csr, rowstart, deg, pq, out);
}

// Round 11
// 165.423 us; speedup vs baseline: 1.1927x; 1.1927x over previous
//
#include <hip/hip_runtime.h>

#define NN 100000   // nodes
#define NE 1000000  // edges
#define FD 64       // feature dim
#define CHK 64      // nodes per block tile in k_l1
#define NBLK 98     // scan blocks: ceil(NN/1024)
#define PADMAX (NE + 15 * NN + 4096)  // padded csr capacity (ints)

// ws layout (4-byte units):
//   deg      : [0, NN)              int
//   rowstart : [NN, 2NN)            int   (PADDED exclusive scan)
//   partial  : [2NN, 2NN+128)       int   (scan block sums)
//   rank     : [2NN+128, +NE)       int   (edge rank within its dst row)
//   csr      : [2NN+128+NE, +PADMAX) int  (byte offsets src<<8, padded rows, pad=0)
//   pq       : next, 4NN floats     (p0,p1,q0,q1 per node)
//   wt       : next, 2*4096 floats  (W1l^T, W1r^T)
// total ~ 16.6 MB

#define OFF_DEG 0
#define OFF_ROW (NN)
#define OFF_PAR (2 * NN)
#define OFF_RANK (2 * NN + 128)
#define OFF_CSR (2 * NN + 128 + NE)
#define OFF_PQ  (OFF_CSR + PADMAX)
#define OFF_WT  (OFF_PQ + 4 * NN)

// ---------------------------------------------------------------------------
// K0: streaming-only init: edge_index -> float output tail + weight transpose.
// (NO atomics here — R10 showed fusing atomics into the stream is 45 us.)
__global__ void k_init(const int* __restrict__ ei, float* __restrict__ edge_out,
                       const float* __restrict__ W1l, const float* __restrict__ W1r,
                       float* __restrict__ wt1l, float* __restrict__ wt1r) {
    const int tid = blockIdx.x * blockDim.x + threadIdx.x;
    if (tid < 2 * NE / 4) {
        const int4 v = *((const int4*)ei + tid);
        float4 f;
        f.x = (float)v.x; f.y = (float)v.y; f.z = (float)v.z; f.w = (float)v.w;
        *((float4*)edge_out + tid) = f;
    }
    if (tid < FD * FD) {
        const int k = tid >> 6, j = tid & 63;
        wt1l[j * FD + k] = W1l[tid];
        wt1r[j * FD + k] = W1r[tid];
    }
}

// ---------------------------------------------------------------------------
// K1: in-degree counts + per-edge rank (int4, 4 edges/thread).
__global__ void k_prep(const int* __restrict__ ei, int* __restrict__ deg,
                       int* __restrict__ rank) {
    const int i = blockIdx.x * blockDim.x + threadIdx.x;
    if (i >= NE / 4) return;
    const int4 d = *((const int4*)(ei + NE) + i);
    int4 r;
    r.x = atomicAdd(&deg[d.x], 1);
    r.y = atomicAdd(&deg[d.y], 1);
    r.z = atomicAdd(&deg[d.z], 1);
    r.w = atomicAdd(&deg[d.w], 1);
    *((int4*)rank + i) = r;
}

// ---------------------------------------------------------------------------
// K2a: per-block (1024-elem) sums of PADDED deg -> partial[b]
__global__ __launch_bounds__(256) void k_scanA(const int* __restrict__ deg,
                                               int* __restrict__ partial) {
    __shared__ int lds[256];
    int t = threadIdx.x;
    int base = blockIdx.x * 1024 + t * 4;
    int s_t = 0;
    if (base < NN) {  // NN % 4 == 0
        int4 v = *(const int4*)(deg + base);
        s_t = ((v.x + 15) & ~15) + ((v.y + 15) & ~15) +
              ((v.z + 15) & ~15) + ((v.w + 15) & ~15);
    }
    lds[t] = s_t;
    __syncthreads();
    for (int s = 128; s; s >>= 1) {
        if (t < s) lds[t] += lds[t + s];
        __syncthreads();
    }
    if (t == 0) partial[blockIdx.x] = lds[0];
}

// K2b: block offset + intra-block exclusive scan of PADDED deg -> rowstart[i]
__global__ __launch_bounds__(256) void k_scanB(const int* __restrict__ deg,
                                               const int* __restrict__ partial,
                                               int* __restrict__ rowstart) {
    __shared__ int lds[256];
    int t = threadIdx.x, b = blockIdx.x;
    lds[t] = (t < b && t < NBLK) ? partial[t] : 0;
    __syncthreads();
    for (int s = 128; s; s >>= 1) {
        if (t < s) lds[t] += lds[t + s];
        __syncthreads();
    }
    int bo = lds[0];
    __syncthreads();

    int base = b * 1024 + t * 4;
    int4 v = make_int4(0, 0, 0, 0);
    if (base < NN) v = *(const int4*)(deg + base);
    int4 p;
    p.x = (v.x + 15) & ~15;
    p.y = (v.y + 15) & ~15;
    p.z = (v.z + 15) & ~15;
    p.w = (v.w + 15) & ~15;
    int s_t = p.x + p.y + p.z + p.w;

    lds[t] = s_t;
    __syncthreads();
    for (int off = 1; off < 256; off <<= 1) {
        int v2 = lds[t];
        if (t >= off) v2 += lds[t - off];
        __syncthreads();
        lds[t] = v2;
        __syncthreads();
    }
    int excl = lds[t] - s_t;
    if (base < NN) {
        int r = bo + excl;
        int4 out;
        out.x = r;
        out.y = r + p.x;
        out.z = r + p.x + p.y;
        out.w = r + p.x + p.y + p.z;
        *(int4*)(rowstart + base) = out;
    }
}

// ---------------------------------------------------------------------------
// K3: pure scatter: csr[prow[d]+rank[e]] = src<<8 (pre-shifted byte offset).
// Pad slots stay 0 (csr pre-memset) -> they point at x row 0.
__global__ void k_build(const int* __restrict__ ei, const int* __restrict__ rowstart,
                        const int* __restrict__ rank, int* __restrict__ csr) {
    const int i = blockIdx.x * blockDim.x + threadIdx.x;
    if (i >= NE / 4) return;
    const int4 s = *((const int4*)ei + i);
    const int4 d = *((const int4*)(ei + NE) + i);
    const int4 r = *((const int4*)rank + i);
    csr[rowstart[d.x] + r.x] = s.x << 8;
    csr[rowstart[d.y] + r.y] = s.y << 8;
    csr[rowstart[d.z] + r.z] = s.z << 8;
    csr[rowstart[d.w] + r.w] = s.w << 8;
}

// ---------------------------------------------------------------------------
// K4: fused layer-1, one 64-node tile per block (8 waves, 512 threads).
//  phase A: 4 groups of 16 lanes per wave; group owns one node and fetches
//    256B neighbor rows as float4. PADDED rows: inner loop is pure
//    {shfl, load, 4xfadd} — no per-edge clamp/mask. Pad loads hit x row 0
//    (same addr -> L1 broadcast); corrected by acc -= npad * x0 per node.
//    8-deep register batches fenced by sched_barrier(0).
//  phase B: lane = node, wave w covers k-slice [8w, 8w+8); wave-uniform
//    weight loads; relu + W2 fold per-lane; LDS-atomic combine.
__global__ __launch_bounds__(512, 4) void k_l1(
    const int* __restrict__ csr, const int* __restrict__ rowstart,
    const int* __restrict__ deg, const float* __restrict__ x,
    const float* __restrict__ wt1l, const float* __restrict__ b1,
    const float* __restrict__ wt1r,
    const float* __restrict__ W2l, const float* __restrict__ b2,
    const float* __restrict__ W2r,
    float* __restrict__ pq) {
    __shared__ float sT[FD][CHK + 1];   // aggr, transposed
    __shared__ float xT[FD][CHK + 1];   // self x, transposed
    __shared__ float pacc[4 * CHK];
    const int lane = threadIdx.x & 63;
    const int wid = threadIdx.x >> 6;   // 0..7
    const int g = lane >> 4;            // group 0..3
    const int sl = lane & 15;           // lane within group
    const int gb = g << 4;              // group base lane
    const int base = blockIdx.x * CHK;
    const char* xb = (const char*)x;
    const unsigned slb = (unsigned)(sl << 4);

    if (threadIdx.x < 4 * CHK) pacc[threadIdx.x] = 0.f;

    const float4 x0 = *(const float4*)(x + sl * 4);  // row 0 slice (pad target)

    // ---- phase A: 2 rounds x 4 nodes per wave ----
    for (int r = 0; r < 2; ++r) {
        const int nl = wid * 8 + r * 4 + g;  // 0..63
        const int n = base + nl;
        const bool ok = n < NN;
        const int nn = ok ? n : NN - 1;
        const int d = deg[nn];               // group-uniform
        const int rs = rowstart[nn];
        const int pd = (d + 15) & ~15;       // padded degree
        float4 acc = make_float4(0.f, 0.f, 0.f, 0.f);

        int dmax = pd;
        dmax = max(dmax, __shfl_xor(dmax, 16));
        dmax = max(dmax, __shfl_xor(dmax, 32));
        const int nchw = __builtin_amdgcn_readfirstlane(dmax >> 4);  // wave max

        for (int c = 0; c < nchw; ++c) {
            const int jb = c << 4;
            const int ia = min(rs + jb + sl, PADMAX - 1);
            const int raw = csr[ia];               // pre-shifted byte offset
            const int offs = (jb < pd) ? raw : 0;  // invalid chunk -> row 0
#pragma unroll
            for (int half = 0; half < 2; ++half) {
                float4 buf[8];
#pragma unroll
                for (int t = 0; t < 8; ++t) {
                    const unsigned ob = (unsigned)__shfl(offs, gb + half * 8 + t);
                    buf[t] = *(const float4*)(xb + (size_t)(ob + slb));
                }
                __builtin_amdgcn_sched_barrier(0);  // keep 8 loads in flight
#pragma unroll
                for (int t = 0; t < 8; ++t) {
                    acc.x += buf[t].x;
                    acc.y += buf[t].y;
                    acc.z += buf[t].z;
                    acc.w += buf[t].w;
                }
            }
        }
        // remove pad contributions (all pad loads hit row 0)
        const float npad = (float)(nchw * 16 - d);
        acc.x -= npad * x0.x;
        acc.y -= npad * x0.y;
        acc.z -= npad * x0.z;
        acc.w -= npad * x0.w;

        if (ok) {
            const float inv = 1.0f / (float)max(d, 1);
            const float4 xv = *(const float4*)(x + (size_t)nn * FD + sl * 4);
            const int f = sl * 4;
            sT[f + 0][nl] = acc.x * inv;
            sT[f + 1][nl] = acc.y * inv;
            sT[f + 2][nl] = acc.z * inv;
            sT[f + 3][nl] = acc.w * inv;
            xT[f + 0][nl] = xv.x;
            xT[f + 1][nl] = xv.y;
            xT[f + 2][nl] = xv.z;
            xT[f + 3][nl] = xv.w;
        }
    }
    __syncthreads();

    // ---- phase B: lane = node, k-slice [kbase, kbase+8) ----
    const int kbase = __builtin_amdgcn_readfirstlane(wid * 8);
    float h[8];
#pragma unroll
    for (int t = 0; t < 8; ++t) h[t] = b1[kbase + t];
#pragma unroll 4
    for (int j = 0; j < FD; ++j) {
        const float sj = sT[j][lane];
        const float xj = xT[j][lane];
        const float* wl = wt1l + j * FD + kbase;
        const float* wr = wt1r + j * FD + kbase;
#pragma unroll
        for (int t = 0; t < 8; ++t) h[t] += sj * wl[t] + xj * wr[t];
    }

    float p0 = 0.f, p1 = 0.f, q0 = 0.f, q1 = 0.f;
#pragma unroll
    for (int t = 0; t < 8; ++t) {
        const float r = fmaxf(h[t], 0.f);
        p0 += r * W2l[kbase + t];
        p1 += r * W2l[FD + kbase + t];
        q0 += r * W2r[kbase + t];
        q1 += r * W2r[FD + kbase + t];
    }
    atomicAdd(&pacc[0 * CHK + lane], p0);
    atomicAdd(&pacc[1 * CHK + lane], p1);
    atomicAdd(&pacc[2 * CHK + lane], q0);
    atomicAdd(&pacc[3 * CHK + lane], q1);
    __syncthreads();

    // ---- write pq: thread t -> (node t>>2, comp t&3), coalesced ----
    {
        const int t = threadIdx.x;
        if (t < 4 * CHK) {
            const int n = base + (t >> 2);
            if (n < NN) {
                const int c = t & 3;
                float v = pacc[c * CHK + (t >> 2)];
                if (c == 2) v += b2[0];
                if (c == 3) v += b2[1];
                pq[(size_t)n * 4 + c] = v;
            }
        }
    }
}

// ---------------------------------------------------------------------------
// K5: layer-2 mean aggregation of p + final add. 16 lanes per node,
//     4 nodes per wave. csr holds src<<8; pq byte offset = (src<<8)>>4.
__global__ void k_l2(const int* __restrict__ csr, const int* __restrict__ rowstart,
                     const int* __restrict__ deg, const float* __restrict__ pq,
                     float* __restrict__ out) {
    const int gw = (blockIdx.x * blockDim.x + threadIdx.x) >> 6;
    const int lane = threadIdx.x & 63;
    const int sub = lane >> 4;   // node within wave
    const int sl = lane & 15;    // lane within 16-group
    const int n = gw * 4 + sub;
    if (n >= NN) return;
    const int rs = rowstart[n];
    const int d = deg[n];
    const char* pb = (const char*)pq;
    float a0 = 0.f, a1 = 0.f;
    for (int i = sl; i < d; i += 16) {
        const unsigned v = (unsigned)csr[rs + i];
        const float2 p = *(const float2*)(pb + (size_t)(v >> 4));
        a0 += p.x;
        a1 += p.y;
    }
#pragma unroll
    for (int off = 8; off; off >>= 1) {
        a0 += __shfl_xor(a0, off);
        a1 += __shfl_xor(a1, off);
    }
    if (sl == 0) {
        const float inv = 1.0f / (float)max(d, 1);
        const float2 q = *(const float2*)(pq + 4 * (size_t)n + 2);
        *(float2*)(out + 2 * (size_t)n) = make_float2(a0 * inv + q.x, a1 * inv + q.y);
    }
}

// ---------------------------------------------------------------------------
extern "C" void kernel_launch(void* const* d_in, const int* in_sizes, int n_in,
                              void* d_out, int out_size, void* d_ws, size_t ws_size,
                              hipStream_t stream) {
    const float* x   = (const float*)d_in[0];
    const int*   ei  = (const int*)d_in[1];
    const float* W1l = (const float*)d_in[2];
    const float* b1  = (const float*)d_in[3];
    const float* W1r = (const float*)d_in[4];
    const float* W2l = (const float*)d_in[5];
    const float* b2  = (const float*)d_in[6];
    const float* W2r = (const float*)d_in[7];

    float* out      = (float*)d_out;   // N*2 floats
    float* edge_out = out + 2 * NN;    // 2*E floats (edge_index as float)

    int*   wsi      = (int*)d_ws;
    int*   deg      = wsi + OFF_DEG;
    int*   rowstart = wsi + OFF_ROW;
    int*   partial  = wsi + OFF_PAR;
    int*   rank     = wsi + OFF_RANK;
    int*   csr      = wsi + OFF_CSR;
    float* pq       = (float*)d_ws + OFF_PQ;
    float* wt1l     = (float*)d_ws + OFF_WT;
    float* wt1r     = wt1l + FD * FD;

    hipMemsetAsync(deg, 0, (size_t)NN * sizeof(int), stream);
    hipMemsetAsync(csr, 0, (size_t)PADMAX * sizeof(int), stream);

    k_init<<<(2 * NE / 4 + 255) / 256, 256, 0, stream>>>(
        ei, edge_out, W1l, W1r, wt1l, wt1r);
    k_prep<<<(NE / 4 + 255) / 256, 256, 0, stream>>>(ei, deg, rank);
    k_scanA<<<NBLK, 256, 0, stream>>>(deg, partial);
    k_scanB<<<NBLK, 256, 0, stream>>>(deg, partial, rowstart);
    k_build<<<(NE / 4 + 255) / 256, 256, 0, stream>>>(ei, rowstart, rank, csr);
    k_l1<<<(NN + CHK - 1) / CHK, 512, 0, stream>>>(csr, rowstart, deg, x,
                                                   wt1l, b1, wt1r,
                                                   W2l, b2, W2r, pq);
    k_l2<<<((NN + 3) / 4 * 64 + 255) / 256, 256, 0, stream>>>(
        csr, rowstart, deg, pq, out);
}

// Round 12
// 151.302 us; speedup vs baseline: 1.3040x; 1.0933x over previous
//
#include <hip/hip_runtime.h>
#include <hip/hip_fp16.h>

#define NN 100000   // nodes
#define NE 1000000  // edges
#define FD 64       // feature dim
#define CHK 64      // nodes per block tile in k_l1
#define NBLK 98     // scan blocks: ceil(NN/1024)

// ws layout (4-byte units):
//   deg      : [0, NN)              int
//   rowstart : [NN, 2NN)            int   (exclusive scan of deg)
//   partial  : [2NN, 2NN+128)       int   (scan block sums)
//   rank     : [2NN+128, +NE)       int   (edge rank within its dst row)
//   csr      : [2NN+128+NE, +NE)    int   (pre-shifted byte offsets src<<7)
//   pq       : next, 4NN floats
//   wt       : next, 2*4096 floats  (W1l^T, W1r^T)
//   xh       : next, (NN+1)*64 halves (f16 copy of x; row NN = zeros)
// total ~ 22.8 MB

#define OFF_DEG 0
#define OFF_ROW (NN)
#define OFF_PAR (2 * NN)
#define OFF_RANK (2 * NN + 128)
#define OFF_CSR (2 * NN + 128 + NE)
#define OFF_PQ  (2 * NN + 128 + 2 * NE)
#define OFF_WT  (OFF_PQ + 4 * NN)
#define OFF_XH  (OFF_WT + 2 * FD * FD)   // float-index; 16B-aligned (checked)

struct alignas(16) H8 { __half2 h[4]; };

// ---------------------------------------------------------------------------
// K0: x -> f16 copy (8 elems/thread), zero pad row, weight transpose.
__global__ void k_cast(const float* __restrict__ x, __half* __restrict__ xh,
                       const float* __restrict__ W1l, const float* __restrict__ W1r,
                       float* __restrict__ wt1l, float* __restrict__ wt1r) {
    const int tid = blockIdx.x * blockDim.x + threadIdx.x;
    const int NC = NN * FD / 8;  // 800000
    if (tid < NC) {
        const float4 a = *((const float4*)x + (size_t)tid * 2);
        const float4 b = *((const float4*)x + (size_t)tid * 2 + 1);
        H8 o;
        o.h[0] = __floats2half2_rn(a.x, a.y);
        o.h[1] = __floats2half2_rn(a.z, a.w);
        o.h[2] = __floats2half2_rn(b.x, b.y);
        o.h[3] = __floats2half2_rn(b.z, b.w);
        *((H8*)xh + tid) = o;
    } else if (tid < NC + 8) {
        H8 z;
        z.h[0] = z.h[1] = z.h[2] = z.h[3] = __float2half2_rn(0.f);
        *((H8*)(xh + (size_t)NN * FD) + (tid - NC)) = z;
    }
    if (tid < FD * FD) {
        const int k = tid >> 6, j = tid & 63;
        wt1l[j * FD + k] = W1l[tid];
        wt1r[j * FD + k] = W1r[tid];
    }
}

// ---------------------------------------------------------------------------
// K1: in-degree counts + per-edge rank (int4, 4 edges/thread).
__global__ void k_prep(const int* __restrict__ ei, int* __restrict__ deg,
                       int* __restrict__ rank) {
    const int i = blockIdx.x * blockDim.x + threadIdx.x;
    if (i >= NE / 4) return;
    const int4 d = *((const int4*)(ei + NE) + i);
    int4 r;
    r.x = atomicAdd(&deg[d.x], 1);
    r.y = atomicAdd(&deg[d.y], 1);
    r.z = atomicAdd(&deg[d.z], 1);
    r.w = atomicAdd(&deg[d.w], 1);
    *((int4*)rank + i) = r;
}

// ---------------------------------------------------------------------------
// K2a: per-block (1024-elem) sums of deg -> partial[b]
__global__ __launch_bounds__(256) void k_scanA(const int* __restrict__ deg,
                                               int* __restrict__ partial) {
    __shared__ int lds[256];
    int t = threadIdx.x;
    int base = blockIdx.x * 1024 + t * 4;
    int s_t = 0;
    if (base < NN) {  // NN % 4 == 0
        int4 v = *(const int4*)(deg + base);
        s_t = v.x + v.y + v.z + v.w;
    }
    lds[t] = s_t;
    __syncthreads();
    for (int s = 128; s; s >>= 1) {
        if (t < s) lds[t] += lds[t + s];
        __syncthreads();
    }
    if (t == 0) partial[blockIdx.x] = lds[0];
}

// K2b: block offset + intra-block exclusive scan -> rowstart[i]
__global__ __launch_bounds__(256) void k_scanB(const int* __restrict__ deg,
                                               const int* __restrict__ partial,
                                               int* __restrict__ rowstart) {
    __shared__ int lds[256];
    int t = threadIdx.x, b = blockIdx.x;
    lds[t] = (t < b && t < NBLK) ? partial[t] : 0;
    __syncthreads();
    for (int s = 128; s; s >>= 1) {
        if (t < s) lds[t] += lds[t + s];
        __syncthreads();
    }
    int bo = lds[0];
    __syncthreads();

    int base = b * 1024 + t * 4;
    int4 v = make_int4(0, 0, 0, 0);
    if (base < NN) v = *(const int4*)(deg + base);
    int s_t = v.x + v.y + v.z + v.w;

    lds[t] = s_t;
    __syncthreads();
    for (int off = 1; off < 256; off <<= 1) {
        int v2 = lds[t];
        if (t >= off) v2 += lds[t - off];
        __syncthreads();
        lds[t] = v2;
        __syncthreads();
    }
    int excl = lds[t] - s_t;
    if (base < NN) {
        int r = bo + excl;
        int4 out;
        out.x = r;
        out.y = r + v.x;
        out.z = r + v.x + v.y;
        out.w = r + v.x + v.y + v.z;
        *(int4*)(rowstart + base) = out;
    }
}

// ---------------------------------------------------------------------------
// K3: csr scatter (src<<7 byte offsets) + edge_index float conversion
//     (reads ei anyway; both write streams are non-atomic).
__global__ void k_build(const int* __restrict__ ei, const int* __restrict__ rowstart,
                        const int* __restrict__ rank, int* __restrict__ csr,
                        float* __restrict__ edge_out) {
    const int i = blockIdx.x * blockDim.x + threadIdx.x;
    if (i >= NE / 4) return;
    const int4 s = *((const int4*)ei + i);
    const int4 d = *((const int4*)(ei + NE) + i);
    const int4 r = *((const int4*)rank + i);
    csr[rowstart[d.x] + r.x] = s.x << 7;
    csr[rowstart[d.y] + r.y] = s.y << 7;
    csr[rowstart[d.z] + r.z] = s.z << 7;
    csr[rowstart[d.w] + r.w] = s.w << 7;
    float4 fs, fd;
    fs.x = (float)s.x; fs.y = (float)s.y; fs.z = (float)s.z; fs.w = (float)s.w;
    fd.x = (float)d.x; fd.y = (float)d.y; fd.z = (float)d.z; fd.w = (float)d.w;
    *((float4*)edge_out + i) = fs;
    *((float4*)(edge_out + NE) + i) = fd;
}

// ---------------------------------------------------------------------------
// K4: fused layer-1, 64-node tile per block (8 waves, 512 threads).
//  phase A: 8 groups of 8 lanes per wave; group owns ONE node; lane loads
//    16B = 8 f16 of a 128B neighbor row -> one wave-load covers 8 rows.
//    Accumulate with v_pk_add_f16 (4/row, no converts). Out-of-range slots
//    redirect to the zero row (exact, maskless). 8-deep batches + sched_barrier.
//  phase B: lane = node, wave w covers k-slice [8w,8w+8); wave-uniform weight
//    loads; relu + W2 fold per-lane; LDS-atomic combine.
__global__ __launch_bounds__(512, 4) void k_l1(
    const int* __restrict__ csr, const int* __restrict__ rowstart,
    const int* __restrict__ deg, const __half* __restrict__ xh,
    const float* __restrict__ wt1l, const float* __restrict__ b1,
    const float* __restrict__ wt1r,
    const float* __restrict__ W2l, const float* __restrict__ b2,
    const float* __restrict__ W2r,
    float* __restrict__ pq) {
    __shared__ float sT[FD][CHK + 1];
    __shared__ float xT[FD][CHK + 1];
    __shared__ float pacc[4 * CHK];
    const int lane = threadIdx.x & 63;
    const int wid = threadIdx.x >> 6;   // 0..7
    const int g = lane >> 3;            // group 0..7
    const int sl = lane & 7;            // lane within group
    const int gb = g << 3;              // group base lane
    const int base = blockIdx.x * CHK;
    const char* xb = (const char*)xh;
    const unsigned slb = (unsigned)(sl << 4);   // 16B per lane
    const int ZOFF = NN << 7;                   // zero-row byte offset

    if (threadIdx.x < 4 * CHK) pacc[threadIdx.x] = 0.f;

    // ---- phase A: one node per group (8 nodes per wave) ----
    const int nl = wid * 8 + g;         // 0..63
    const int n = base + nl;
    const bool ok = n < NN;
    const int nn = ok ? n : NN - 1;
    const int d = deg[nn];              // group-uniform
    const int rs = rowstart[nn];

    int dmax = d;
    dmax = max(dmax, __shfl_xor(dmax, 8));
    dmax = max(dmax, __shfl_xor(dmax, 16));
    dmax = max(dmax, __shfl_xor(dmax, 32));
    const int nch = __builtin_amdgcn_readfirstlane((dmax + 7) >> 3);

    H8 acc;
    acc.h[0] = acc.h[1] = acc.h[2] = acc.h[3] = __float2half2_rn(0.f);

    for (int c = 0; c < nch; ++c) {
        const int jb = c << 3;
        const int ia = min(rs + jb + sl, NE - 1);
        const int raw = csr[ia];                       // pre-shifted src<<7
        const int offs = (jb + sl < d) ? raw : ZOFF;   // invalid -> zero row
        H8 buf[8];
#pragma unroll
        for (int t = 0; t < 8; ++t) {
            const unsigned ob = (unsigned)__shfl(offs, gb + t);
            buf[t] = *(const H8*)(xb + (size_t)(ob + slb));
        }
        __builtin_amdgcn_sched_barrier(0);  // keep 8 row-loads in flight
#pragma unroll
        for (int t = 0; t < 8; ++t) {
            acc.h[0] = __hadd2(acc.h[0], buf[t].h[0]);
            acc.h[1] = __hadd2(acc.h[1], buf[t].h[1]);
            acc.h[2] = __hadd2(acc.h[2], buf[t].h[2]);
            acc.h[3] = __hadd2(acc.h[3], buf[t].h[3]);
        }
    }

    if (ok) {
        const float inv = 1.0f / (float)max(d, 1);
        const H8 xv = *(const H8*)(xb + (size_t)(((unsigned)nn << 7) + slb));
        const int f = sl * 8;
#pragma unroll
        for (int t = 0; t < 4; ++t) {
            const float2 sv = __half22float2(acc.h[t]);
            const float2 xvf = __half22float2(xv.h[t]);
            sT[f + 2 * t + 0][nl] = sv.x * inv;
            sT[f + 2 * t + 1][nl] = sv.y * inv;
            xT[f + 2 * t + 0][nl] = xvf.x;
            xT[f + 2 * t + 1][nl] = xvf.y;
        }
    }
    __syncthreads();

    // ---- phase B: lane = node, k-slice [kbase, kbase+8) ----
    const int kbase = __builtin_amdgcn_readfirstlane(wid * 8);
    float h[8];
#pragma unroll
    for (int t = 0; t < 8; ++t) h[t] = b1[kbase + t];
#pragma unroll 4
    for (int j = 0; j < FD; ++j) {
        const float sj = sT[j][lane];
        const float xj = xT[j][lane];
        const float* wl = wt1l + j * FD + kbase;
        const float* wr = wt1r + j * FD + kbase;
#pragma unroll
        for (int t = 0; t < 8; ++t) h[t] += sj * wl[t] + xj * wr[t];
    }

    float p0 = 0.f, p1 = 0.f, q0 = 0.f, q1 = 0.f;
#pragma unroll
    for (int t = 0; t < 8; ++t) {
        const float r = fmaxf(h[t], 0.f);
        p0 += r * W2l[kbase + t];
        p1 += r * W2l[FD + kbase + t];
        q0 += r * W2r[kbase + t];
        q1 += r * W2r[FD + kbase + t];
    }
    atomicAdd(&pacc[0 * CHK + lane], p0);
    atomicAdd(&pacc[1 * CHK + lane], p1);
    atomicAdd(&pacc[2 * CHK + lane], q0);
    atomicAdd(&pacc[3 * CHK + lane], q1);
    __syncthreads();

    // ---- write pq: thread t -> (node t>>2, comp t&3), coalesced ----
    {
        const int t = threadIdx.x;
        if (t < 4 * CHK) {
            const int nw = base + (t >> 2);
            if (nw < NN) {
                const int c = t & 3;
                float v = pacc[c * CHK + (t >> 2)];
                if (c == 2) v += b2[0];
                if (c == 3) v += b2[1];
                pq[(size_t)nw * 4 + c] = v;
            }
        }
    }
}

// ---------------------------------------------------------------------------
// K5: layer-2 mean aggregation of p + final add. 16 lanes per node,
//     4 nodes per wave. csr holds src<<7; pq byte offset = src*16 = v>>3.
__global__ void k_l2(const int* __restrict__ csr, const int* __restrict__ rowstart,
                     const int* __restrict__ deg, const float* __restrict__ pq,
                     float* __restrict__ out) {
    const int gw = (blockIdx.x * blockDim.x + threadIdx.x) >> 6;
    const int lane = threadIdx.x & 63;
    const int sub = lane >> 4;   // node within wave
    const int sl = lane & 15;    // lane within 16-group
    const int n = gw * 4 + sub;
    if (n >= NN) return;
    const int rs = rowstart[n];
    const int d = deg[n];
    const char* pb = (const char*)pq;
    float a0 = 0.f, a1 = 0.f;
    for (int i = sl; i < d; i += 16) {
        const unsigned v = (unsigned)csr[rs + i];
        const float2 p = *(const float2*)(pb + (size_t)(v >> 3));
        a0 += p.x;
        a1 += p.y;
    }
#pragma unroll
    for (int off = 8; off; off >>= 1) {
        a0 += __shfl_xor(a0, off);
        a1 += __shfl_xor(a1, off);
    }
    if (sl == 0) {
        const float inv = 1.0f / (float)max(d, 1);
        const float2 q = *(const float2*)(pq + 4 * (size_t)n + 2);
        *(float2*)(out + 2 * (size_t)n) = make_float2(a0 * inv + q.x, a1 * inv + q.y);
    }
}

// ---------------------------------------------------------------------------
extern "C" void kernel_launch(void* const* d_in, const int* in_sizes, int n_in,
                              void* d_out, int out_size, void* d_ws, size_t ws_size,
                              hipStream_t stream) {
    const float* x   = (const float*)d_in[0];
    const int*   ei  = (const int*)d_in[1];
    const float* W1l = (const float*)d_in[2];
    const float* b1  = (const float*)d_in[3];
    const float* W1r = (const float*)d_in[4];
    const float* W2l = (const float*)d_in[5];
    const float* b2  = (const float*)d_in[6];
    const float* W2r = (const float*)d_in[7];

    float* out      = (float*)d_out;   // N*2 floats
    float* edge_out = out + 2 * NN;    // 2*E floats (edge_index as float)

    int*   wsi      = (int*)d_ws;
    int*   deg      = wsi + OFF_DEG;
    int*   rowstart = wsi + OFF_ROW;
    int*   partial  = wsi + OFF_PAR;
    int*   rank     = wsi + OFF_RANK;
    int*   csr      = wsi + OFF_CSR;
    float* pq       = (float*)d_ws + OFF_PQ;
    float* wt1l     = (float*)d_ws + OFF_WT;
    float* wt1r     = wt1l + FD * FD;
    __half* xh      = (__half*)((float*)d_ws + OFF_XH);

    hipMemsetAsync(deg, 0, (size_t)NN * sizeof(int), stream);

    k_cast<<<(NN * FD / 8 + 8 + 255) / 256, 256, 0, stream>>>(
        x, xh, W1l, W1r, wt1l, wt1r);
    k_prep<<<(NE / 4 + 255) / 256, 256, 0, stream>>>(ei, deg, rank);
    k_scanA<<<NBLK, 256, 0, stream>>>(deg, partial);
    k_scanB<<<NBLK, 256, 0, stream>>>(deg, partial, rowstart);
    k_build<<<(NE / 4 + 255) / 256, 256, 0, stream>>>(ei, rowstart, rank, csr,
                                                      edge_out);
    k_l1<<<(NN + CHK - 1) / CHK, 512, 0, stream>>>(csr, rowstart, deg, xh,
                                                   wt1l, b1, wt1r,
                                                   W2l, b2, W2r, pq);
    k_l2<<<((NN + 3) / 4 * 64 + 255) / 256, 256, 0, stream>>>(
        csr, rowstart, deg, pq, out);
}

// Round 13
// 137.561 us; speedup vs baseline: 1.4342x; 1.0999x over previous
//
#include <hip/hip_runtime.h>
#include <hip/hip_fp16.h>

#define NN 100000   // nodes
#define NE 1000000  // edges
#define FD 64       // feature dim
#define CHK 64      // nodes per block tile in k_l1
#define NBLK 98     // scan blocks: ceil(NN/1024)

typedef _Float16 f16x2 __attribute__((ext_vector_type(2)));

#if defined(__has_builtin)
#if __has_builtin(__builtin_amdgcn_fdot2)
#define HAVE_FDOT2 1
#endif
#endif

__device__ __forceinline__ float fdot2f(__half2 a, __half2 b, float c) {
#ifdef HAVE_FDOT2
    return __builtin_amdgcn_fdot2(__builtin_bit_cast(f16x2, a),
                                  __builtin_bit_cast(f16x2, b), c, false);
#else
    const float2 af = __half22float2(a), bf = __half22float2(b);
    return c + af.x * bf.x + af.y * bf.y;
#endif
}

// ws layout (4-byte units):
//   deg      : [0, NN)              int
//   rowstart : [NN, 2NN)            int   (exclusive scan of deg)
//   partial  : [2NN, 2NN+128)       int   (scan block sums)
//   rank     : [2NN+128, +NE)       int   (edge rank within its dst row)
//   csr      : [2NN+128+NE, +NE)    int   (pre-shifted byte offsets src<<7)
//   pq       : next, 4NN floats
//   wth      : next, 2*2048 half2   (W1l^T, W1r^T packed f16 [j2][k])
//   xh       : next, (NN+1)*64 halves (f16 copy of x; row NN = zeros)
// total ~ 23.4 MB

#define OFF_DEG 0
#define OFF_ROW (NN)
#define OFF_PAR (2 * NN)
#define OFF_RANK (2 * NN + 128)
#define OFF_CSR (2 * NN + 128 + NE)
#define OFF_PQ  (2 * NN + 128 + 2 * NE)
#define OFF_WTH (OFF_PQ + 4 * NN)        // 2*2048 uints
#define OFF_XH  (OFF_WTH + 2 * 2048)     // 16B-aligned (all terms %4==0)

struct alignas(16) H8 { __half2 h[4]; };

// ---------------------------------------------------------------------------
// K1 (fused): disjoint thread ranges do
//   [0, NE/4)            : in-degree atomics + per-edge rank (int4)
//   [NE/4, +NN*FD/8)     : x -> f16 copy (8 elems/thread)
//   next 8               : zero pad row
//   next 2048            : pack W1l^T,W1r^T to f16 half2 [j2][k]
// The streaming cast hides under the atomic pass (R10 lesson: never make the
// SAME thread do stream+atomic; disjoint waves are fine).
__global__ void k_pc(const int* __restrict__ ei, int* __restrict__ deg,
                     int* __restrict__ rank,
                     const float* __restrict__ x, __half* __restrict__ xh,
                     const float* __restrict__ W1l, const float* __restrict__ W1r,
                     __half2* __restrict__ wt1lh, __half2* __restrict__ wt1rh) {
    const int tid = blockIdx.x * blockDim.x + threadIdx.x;
    const int NC = NN * FD / 8;          // 800000 cast threads
    if (tid < NE / 4) {
        const int4 d = *((const int4*)(ei + NE) + tid);
        int4 r;
        r.x = atomicAdd(&deg[d.x], 1);
        r.y = atomicAdd(&deg[d.y], 1);
        r.z = atomicAdd(&deg[d.z], 1);
        r.w = atomicAdd(&deg[d.w], 1);
        *((int4*)rank + tid) = r;
    } else if (tid < NE / 4 + NC) {
        const int i = tid - NE / 4;
        const float4 a = *((const float4*)x + (size_t)i * 2);
        const float4 b = *((const float4*)x + (size_t)i * 2 + 1);
        H8 o;
        o.h[0] = __floats2half2_rn(a.x, a.y);
        o.h[1] = __floats2half2_rn(a.z, a.w);
        o.h[2] = __floats2half2_rn(b.x, b.y);
        o.h[3] = __floats2half2_rn(b.z, b.w);
        *((H8*)xh + i) = o;
    } else if (tid < NE / 4 + NC + 8) {
        H8 z;
        z.h[0] = z.h[1] = z.h[2] = z.h[3] = __float2half2_rn(0.f);
        *((H8*)(xh + (size_t)NN * FD) + (tid - NE / 4 - NC)) = z;
    } else if (tid < NE / 4 + NC + 8 + 2048) {
        const int i = tid - (NE / 4 + NC + 8);   // j2*64 + k
        const int j2 = i >> 6, k = i & 63;
        wt1lh[i] = __floats2half2_rn(W1l[k * FD + 2 * j2], W1l[k * FD + 2 * j2 + 1]);
        wt1rh[i] = __floats2half2_rn(W1r[k * FD + 2 * j2], W1r[k * FD + 2 * j2 + 1]);
    }
}

// ---------------------------------------------------------------------------
// K2a: per-block (1024-elem) sums of deg -> partial[b]
__global__ __launch_bounds__(256) void k_scanA(const int* __restrict__ deg,
                                               int* __restrict__ partial) {
    __shared__ int lds[256];
    int t = threadIdx.x;
    int base = blockIdx.x * 1024 + t * 4;
    int s_t = 0;
    if (base < NN) {  // NN % 4 == 0
        int4 v = *(const int4*)(deg + base);
        s_t = v.x + v.y + v.z + v.w;
    }
    lds[t] = s_t;
    __syncthreads();
    for (int s = 128; s; s >>= 1) {
        if (t < s) lds[t] += lds[t + s];
        __syncthreads();
    }
    if (t == 0) partial[blockIdx.x] = lds[0];
}

// K2b: block offset + intra-block exclusive scan -> rowstart[i]
__global__ __launch_bounds__(256) void k_scanB(const int* __restrict__ deg,
                                               const int* __restrict__ partial,
                                               int* __restrict__ rowstart) {
    __shared__ int lds[256];
    int t = threadIdx.x, b = blockIdx.x;
    lds[t] = (t < b && t < NBLK) ? partial[t] : 0;
    __syncthreads();
    for (int s = 128; s; s >>= 1) {
        if (t < s) lds[t] += lds[t + s];
        __syncthreads();
    }
    int bo = lds[0];
    __syncthreads();

    int base = b * 1024 + t * 4;
    int4 v = make_int4(0, 0, 0, 0);
    if (base < NN) v = *(const int4*)(deg + base);
    int s_t = v.x + v.y + v.z + v.w;

    lds[t] = s_t;
    __syncthreads();
    for (int off = 1; off < 256; off <<= 1) {
        int v2 = lds[t];
        if (t >= off) v2 += lds[t - off];
        __syncthreads();
        lds[t] = v2;
        __syncthreads();
    }
    int excl = lds[t] - s_t;
    if (base < NN) {
        int r = bo + excl;
        int4 out;
        out.x = r;
        out.y = r + v.x;
        out.z = r + v.x + v.y;
        out.w = r + v.x + v.y + v.z;
        *(int4*)(rowstart + base) = out;
    }
}

// ---------------------------------------------------------------------------
// K3: csr scatter (src<<7 byte offsets) + edge_index float conversion.
__global__ void k_build(const int* __restrict__ ei, const int* __restrict__ rowstart,
                        const int* __restrict__ rank, int* __restrict__ csr,
                        float* __restrict__ edge_out) {
    const int i = blockIdx.x * blockDim.x + threadIdx.x;
    if (i >= NE / 4) return;
    const int4 s = *((const int4*)ei + i);
    const int4 d = *((const int4*)(ei + NE) + i);
    const int4 r = *((const int4*)rank + i);
    csr[rowstart[d.x] + r.x] = s.x << 7;
    csr[rowstart[d.y] + r.y] = s.y << 7;
    csr[rowstart[d.z] + r.z] = s.z << 7;
    csr[rowstart[d.w] + r.w] = s.w << 7;
    float4 fs, fd;
    fs.x = (float)s.x; fs.y = (float)s.y; fs.z = (float)s.z; fs.w = (float)s.w;
    fd.x = (float)d.x; fd.y = (float)d.y; fd.z = (float)d.z; fd.w = (float)d.w;
    *((float4*)edge_out + i) = fs;
    *((float4*)(edge_out + NE) + i) = fd;
}

// ---------------------------------------------------------------------------
// K4: fused layer-1, 64-node tile per block (8 waves, 512 threads).
//  phase A: 8 groups of 8 lanes; group owns one node; lane loads 16B = 8 f16
//    of a 128B neighbor row; v_pk_add_f16 accumulate; invalid slots hit the
//    zero row (exact, maskless); 8-deep batches + sched_barrier.
//  phase B: packed half2 j-pairs: 2 ds_read_b32 per j2 (64 total, half of
//    R12) + v_dot2_f32_f16 with f16 weights (2 MAC/instr, f32 accum).
__global__ __launch_bounds__(512, 8) void k_l1(
    const int* __restrict__ csr, const int* __restrict__ rowstart,
    const int* __restrict__ deg, const __half* __restrict__ xh,
    const __half2* __restrict__ wt1lh, const float* __restrict__ b1,
    const __half2* __restrict__ wt1rh,
    const float* __restrict__ W2l, const float* __restrict__ b2,
    const float* __restrict__ W2r,
    float* __restrict__ pq) {
    __shared__ __half2 sH[FD / 2][CHK + 1];   // 8.3 KB
    __shared__ __half2 xH[FD / 2][CHK + 1];   // 8.3 KB
    __shared__ float pacc[4 * CHK];           // 1 KB
    const int lane = threadIdx.x & 63;
    const int wid = threadIdx.x >> 6;   // 0..7
    const int g = lane >> 3;            // group 0..7
    const int sl = lane & 7;            // lane within group
    const int gb = g << 3;              // group base lane
    const int base = blockIdx.x * CHK;
    const char* xb = (const char*)xh;
    const unsigned slb = (unsigned)(sl << 4);   // 16B per lane
    const int ZOFF = NN << 7;                   // zero-row byte offset

    if (threadIdx.x < 4 * CHK) pacc[threadIdx.x] = 0.f;

    // ---- phase A: one node per group (8 nodes per wave) ----
    const int nl = wid * 8 + g;         // 0..63
    const int n = base + nl;
    const bool ok = n < NN;
    const int nn = ok ? n : NN - 1;
    const int d = deg[nn];              // group-uniform
    const int rs = rowstart[nn];

    int dmax = d;
    dmax = max(dmax, __shfl_xor(dmax, 8));
    dmax = max(dmax, __shfl_xor(dmax, 16));
    dmax = max(dmax, __shfl_xor(dmax, 32));
    const int nch = __builtin_amdgcn_readfirstlane((dmax + 7) >> 3);

    H8 acc;
    acc.h[0] = acc.h[1] = acc.h[2] = acc.h[3] = __float2half2_rn(0.f);

    for (int c = 0; c < nch; ++c) {
        const int jb = c << 3;
        const int ia = min(rs + jb + sl, NE - 1);
        const int raw = csr[ia];                       // pre-shifted src<<7
        const int offs = (jb + sl < d) ? raw : ZOFF;   // invalid -> zero row
        H8 buf[8];
#pragma unroll
        for (int t = 0; t < 8; ++t) {
            const unsigned ob = (unsigned)__shfl(offs, gb + t);
            buf[t] = *(const H8*)(xb + (size_t)(ob + slb));
        }
        __builtin_amdgcn_sched_barrier(0);  // keep 8 row-loads in flight
#pragma unroll
        for (int t = 0; t < 8; ++t) {
            acc.h[0] = __hadd2(acc.h[0], buf[t].h[0]);
            acc.h[1] = __hadd2(acc.h[1], buf[t].h[1]);
            acc.h[2] = __hadd2(acc.h[2], buf[t].h[2]);
            acc.h[3] = __hadd2(acc.h[3], buf[t].h[3]);
        }
    }

    if (ok) {
        const __half2 hinv = __float2half2_rn(1.0f / (float)max(d, 1));
        const H8 xv = *(const H8*)(xb + (size_t)(((unsigned)nn << 7) + slb));
#pragma unroll
        for (int t = 0; t < 4; ++t) {
            sH[sl * 4 + t][nl] = __hmul2(acc.h[t], hinv);
            xH[sl * 4 + t][nl] = xv.h[t];
        }
    }
    __syncthreads();

    // ---- phase B: lane = node, k-slice [kbase, kbase+8), packed j-pairs ----
    const int kbase = __builtin_amdgcn_readfirstlane(wid * 8);
    float h[8];
#pragma unroll
    for (int t = 0; t < 8; ++t) h[t] = b1[kbase + t];
#pragma unroll 4
    for (int j2 = 0; j2 < FD / 2; ++j2) {
        const __half2 sj = sH[j2][lane];
        const __half2 xj = xH[j2][lane];
        const __half2* wl = wt1lh + j2 * FD + kbase;   // wave-uniform
        const __half2* wr = wt1rh + j2 * FD + kbase;
#pragma unroll
        for (int t = 0; t < 8; ++t) {
            h[t] = fdot2f(sj, wl[t], h[t]);
            h[t] = fdot2f(xj, wr[t], h[t]);
        }
    }

    float p0 = 0.f, p1 = 0.f, q0 = 0.f, q1 = 0.f;
#pragma unroll
    for (int t = 0; t < 8; ++t) {
        const float r = fmaxf(h[t], 0.f);
        p0 += r * W2l[kbase + t];
        p1 += r * W2l[FD + kbase + t];
        q0 += r * W2r[kbase + t];
        q1 += r * W2r[FD + kbase + t];
    }
    atomicAdd(&pacc[0 * CHK + lane], p0);
    atomicAdd(&pacc[1 * CHK + lane], p1);
    atomicAdd(&pacc[2 * CHK + lane], q0);
    atomicAdd(&pacc[3 * CHK + lane], q1);
    __syncthreads();

    // ---- write pq: thread t -> (node t>>2, comp t&3), coalesced ----
    {
        const int t = threadIdx.x;
        if (t < 4 * CHK) {
            const int nw = base + (t >> 2);
            if (nw < NN) {
                const int c = t & 3;
                float v = pacc[c * CHK + (t >> 2)];
                if (c == 2) v += b2[0];
                if (c == 3) v += b2[1];
                pq[(size_t)nw * 4 + c] = v;
            }
        }
    }
}

// ---------------------------------------------------------------------------
// K5: layer-2 mean aggregation of p + final add. 16 lanes per node,
//     4 nodes per wave. csr holds src<<7; pq byte offset = src*16 = v>>3.
__global__ void k_l2(const int* __restrict__ csr, const int* __restrict__ rowstart,
                     const int* __restrict__ deg, const float* __restrict__ pq,
                     float* __restrict__ out) {
    const int gw = (blockIdx.x * blockDim.x + threadIdx.x) >> 6;
    const int lane = threadIdx.x & 63;
    const int sub = lane >> 4;   // node within wave
    const int sl = lane & 15;    // lane within 16-group
    const int n = gw * 4 + sub;
    if (n >= NN) return;
    const int rs = rowstart[n];
    const int d = deg[n];
    const char* pb = (const char*)pq;
    float a0 = 0.f, a1 = 0.f;
    for (int i = sl; i < d; i += 16) {
        const unsigned v = (unsigned)csr[rs + i];
        const float2 p = *(const float2*)(pb + (size_t)(v >> 3));
        a0 += p.x;
        a1 += p.y;
    }
#pragma unroll
    for (int off = 8; off; off >>= 1) {
        a0 += __shfl_xor(a0, off);
        a1 += __shfl_xor(a1, off);
    }
    if (sl == 0) {
        const float inv = 1.0f / (float)max(d, 1);
        const float2 q = *(const float2*)(pq + 4 * (size_t)n + 2);
        *(float2*)(out + 2 * (size_t)n) = make_float2(a0 * inv + q.x, a1 * inv + q.y);
    }
}

// ---------------------------------------------------------------------------
extern "C" void kernel_launch(void* const* d_in, const int* in_sizes, int n_in,
                              void* d_out, int out_size, void* d_ws, size_t ws_size,
                              hipStream_t stream) {
    const float* x   = (const float*)d_in[0];
    const int*   ei  = (const int*)d_in[1];
    const float* W1l = (const float*)d_in[2];
    const float* b1  = (const float*)d_in[3];
    const float* W1r = (const float*)d_in[4];
    const float* W2l = (const float*)d_in[5];
    const float* b2  = (const float*)d_in[6];
    const float* W2r = (const float*)d_in[7];

    float* out      = (float*)d_out;   // N*2 floats
    float* edge_out = out + 2 * NN;    // 2*E floats (edge_index as float)

    int*    wsi      = (int*)d_ws;
    int*    deg      = wsi + OFF_DEG;
    int*    rowstart = wsi + OFF_ROW;
    int*    partial  = wsi + OFF_PAR;
    int*    rank     = wsi + OFF_RANK;
    int*    csr      = wsi + OFF_CSR;
    float*  pq       = (float*)d_ws + OFF_PQ;
    __half2* wt1lh   = (__half2*)((float*)d_ws + OFF_WTH);
    __half2* wt1rh   = wt1lh + 2048;
    __half*  xh      = (__half*)((float*)d_ws + OFF_XH);

    hipMemsetAsync(deg, 0, (size_t)NN * sizeof(int), stream);

    const int npc = NE / 4 + NN * FD / 8 + 8 + 2048;
    k_pc<<<(npc + 255) / 256, 256, 0, stream>>>(ei, deg, rank, x, xh,
                                                W1l, W1r, wt1lh, wt1rh);
    k_scanA<<<NBLK, 256, 0, stream>>>(deg, partial);
    k_scanB<<<NBLK, 256, 0, stream>>>(deg, partial, rowstart);
    k_build<<<(NE / 4 + 255) / 256, 256, 0, stream>>>(ei, rowstart, rank, csr,
                                                      edge_out);
    k_l1<<<(NN + CHK - 1) / CHK, 512, 0, stream>>>(csr, rowstart, deg, xh,
                                                   wt1lh, b1, wt1rh,
                                                   W2l, b2, W2r, pq);
    k_l2<<<((NN + 3) / 4 * 64 + 255) / 256, 256, 0, stream>>>(
        csr, rowstart, deg, pq, out);
}